// Round 2
// baseline (154.205 us; speedup 1.0000x reference)
//
#include <hip/hip_runtime.h>

// YOLO-style loss: y_pred (1024,28,28,30) f32, y_true (1024,28,28,5) f32 -> scalar f32.
// DRAM floor: 112.4 MB read @ ~6.3 TB/s ~= 18 us. Harness poison fills (2 x 385 MB ~= 113 us)
// dominate dur_us and are not controllable from kernel_launch.
// R5 barrier-free wave-private LDS staging: ~40us kernel, dur 152.
// R6 persistent waves + dbuf + global_load_lds + inline vmcnt(14): dur 153 (NO GAIN).
//   Post-mortem: compiler-visible LDS reads alias the DMA dest -> SIInsertWaitcnts
//   legalizes them with its own s_waitcnt vmcnt(0) before the first ds_read ->
//   prefetch drained every iteration (same drain the guide documents at s_barrier).
// R7 (this): make LDS reads OPAQUE. All 20 reads per tile are one volatile asm block
//   (15x ds_read_b64 + 5x ds_read_b32 + s_waitcnt lgkmcnt(0) inside), no "memory"
//   clobber anywhere, early-clobber outputs, sched_barrier(0) pinning stage->vmcnt.
//   Now the ONLY DMA->read ordering is our counted s_waitcnt vmcnt(14): next tile's
//   14 DMA ops genuinely stay in flight across compute (T3/T4: never drain to 0).

#define S_GRID 28
#define N_CELLS (1024 * S_GRID * S_GRID)     // 802816
#define CPW 64                               // cells per wave-tile
#define N_TILES (N_CELLS / CPW)              // 12544
#define WPB 2                                // waves per block
#define BLOCK (WPB * 64)                     // 128
#define NBLOCKS 1024                         // 4 resident blocks/CU * 256 CU
#define NWAVES (NBLOCKS * WPB)               // 2048 persistent waves
#define SLAB_FLOATS (CPW * 30 + CPW * 5)     // 2240 floats = 8960 B per (wave,buf)
#define SLAB_BYTES (SLAB_FLOATS * 4)

typedef unsigned int u32;
typedef float v2f __attribute__((ext_vector_type(2)));

__device__ __forceinline__ void async16(const float* g, float* l) {
    __builtin_amdgcn_global_load_lds((const __attribute__((address_space(1))) u32*)g,
                                     (__attribute__((address_space(3))) u32*)l, 16, 0, 0);
}
__device__ __forceinline__ void async4(const float* g, float* l) {
    __builtin_amdgcn_global_load_lds((const __attribute__((address_space(1))) u32*)g,
                                     (__attribute__((address_space(3))) u32*)l, 4, 0, 0);
}
__device__ __forceinline__ u32 lds_off(const void* p) {
    // AS3 pointers are 32-bit LDS byte offsets
    return (u32)(unsigned long long)(__attribute__((address_space(3))) const void*)p;
}

// Issue the 14 DMA ops staging one tile (1920 pred floats + 320 true floats).
// LDS dst is wave-uniform base (+ lane*size applied by HW); global src is per-lane.
__device__ __forceinline__ void stage(const float* __restrict__ yp,
                                      const float* __restrict__ yt,
                                      int tile, int lane, float* slab) {
    const float* gp = yp + (size_t)tile * (CPW * 30);
#pragma unroll
    for (int j = 0; j < 7; ++j)                      // 7 * 1024 B
        async16(gp + j * 256 + lane * 4, slab + j * 256);
    async4(gp + 1792 + lane, slab + 1792);           // + 2 * 256 B = 7680 B pred
    async4(gp + 1856 + lane, slab + 1856);
    const float* gt = yt + (size_t)tile * (CPW * 5);
#pragma unroll
    for (int j = 0; j < 5; ++j)                      // 5 * 256 B = 1280 B true
        async4(gt + j * 64 + lane, slab + 1920 + j * 64);
}

__device__ __forceinline__ float iou_calc(float bx, float by, float bw, float bh,
                                          float tx, float ty, float tw, float th,
                                          float gi, float gj) {
    float acx = (gj + bx) * 8.0f;
    float acy = (gi + by) * 8.0f;
    float aw  = bw * 224.0f;
    float ah  = bh * 224.0f;
    float ax1 = acx - aw * 0.5f, ax2 = acx + aw * 0.5f;
    float ay1 = acy - ah * 0.5f, ay2 = acy + ah * 0.5f;
    float bcx = (gj + tx) * 8.0f;
    float bcy = (gi + ty) * 8.0f;
    float btw = tw * 224.0f;
    float bth = th * 224.0f;
    float bx1 = bcx - btw * 0.5f, bx2 = bcx + btw * 0.5f;
    float by1 = bcy - bth * 0.5f, by2 = bcy + bth * 0.5f;

    float iw = fmaxf(fminf(ax2, bx2) - fmaxf(ax1, bx1), 0.0f);
    float ih = fmaxf(fminf(ay2, by2) - fmaxf(ay1, by1), 0.0f);
    float inter = iw * ih;
    float area_a = fmaxf(ax2 - ax1, 0.0f) * fmaxf(ay2 - ay1, 0.0f);
    float area_b = fmaxf(bx2 - bx1, 0.0f) * fmaxf(by2 - by1, 0.0f);
    return inter / (area_a + area_b - inter + 1e-12f);
}

__global__ __launch_bounds__(BLOCK, 2) void yolo_loss_kernel(const float* __restrict__ yp,
                                                             const float* __restrict__ yt,
                                                             float* __restrict__ partials) {
    // wave-private double-buffered slabs, flat layout (DMA writes linearly)
    __shared__ __align__(16) float lds[WPB][2][SLAB_FLOATS];   // 35840 B/block

    int tid  = threadIdx.x;
    int lane = tid & 63;
    int wave = tid >> 6;
    int gwave = blockIdx.x * WPB + wave;

    // 32-bit LDS byte offsets for the opaque asm reads
    u32 base0 = lds_off(&lds[wave][0][0]);
    u32 pa0 = base0 + (u32)lane * 120u;                 // pred: 30 floats/cell
    u32 ta0 = base0 + 1920u * 4u + (u32)lane * 20u;     // true: 5 floats/cell

    float acc = 0.0f;
    int buf = 0;

    // prologue: prefetch first tile (every wave has >=1: NWAVES <= N_TILES)
    stage(yp, yt, gwave, lane, lds[wave][0]);

    for (int t = gwave; t < N_TILES; t += NWAVES) {
        int tn = t + NWAVES;
        if (tn < N_TILES) {
            // issue next tile's 14 DMA ops into the other buffer, then wait so
            // that ONLY those 14 remain outstanding -> tile t complete in LDS
            stage(yp, yt, tn, lane, lds[wave][buf ^ 1]);
            __builtin_amdgcn_sched_barrier(0);
            asm volatile("s_waitcnt vmcnt(14)" ::);
        } else {
            __builtin_amdgcn_sched_barrier(0);
            asm volatile("s_waitcnt vmcnt(0)" ::);
        }
        __builtin_amdgcn_sched_barrier(0);

        u32 boff = (u32)buf * (u32)SLAB_BYTES;
        u32 pa = pa0 + boff;
        u32 ta = ta0 + boff;

        // opaque LDS reads: compiler cannot see these alias the DMA dest, so it
        // cannot legalize them with its own vmcnt(0). lgkmcnt(0) inside the block
        // covers all consumers via the output data dependency.
        v2f q0, q1, q2, q3, q4, q5, q6, q7, q8, q9, q10, q11, q12, q13, q14;
        float tc, tx, ty, tw, th;
        asm volatile(
            "ds_read_b64 %0, %20 offset:0\n\t"
            "ds_read_b64 %1, %20 offset:8\n\t"
            "ds_read_b64 %2, %20 offset:16\n\t"
            "ds_read_b64 %3, %20 offset:24\n\t"
            "ds_read_b64 %4, %20 offset:32\n\t"
            "ds_read_b64 %5, %20 offset:40\n\t"
            "ds_read_b64 %6, %20 offset:48\n\t"
            "ds_read_b64 %7, %20 offset:56\n\t"
            "ds_read_b64 %8, %20 offset:64\n\t"
            "ds_read_b64 %9, %20 offset:72\n\t"
            "ds_read_b64 %10, %20 offset:80\n\t"
            "ds_read_b64 %11, %20 offset:88\n\t"
            "ds_read_b64 %12, %20 offset:96\n\t"
            "ds_read_b64 %13, %20 offset:104\n\t"
            "ds_read_b64 %14, %20 offset:112\n\t"
            "ds_read_b32 %15, %21 offset:0\n\t"
            "ds_read_b32 %16, %21 offset:4\n\t"
            "ds_read_b32 %17, %21 offset:8\n\t"
            "ds_read_b32 %18, %21 offset:12\n\t"
            "ds_read_b32 %19, %21 offset:16\n\t"
            "s_waitcnt lgkmcnt(0)"
            : "=&v"(q0), "=&v"(q1), "=&v"(q2), "=&v"(q3), "=&v"(q4),
              "=&v"(q5), "=&v"(q6), "=&v"(q7), "=&v"(q8), "=&v"(q9),
              "=&v"(q10), "=&v"(q11), "=&v"(q12), "=&v"(q13), "=&v"(q14),
              "=&v"(tc), "=&v"(tx), "=&v"(ty), "=&v"(tw), "=&v"(th)
            : "v"(pa), "v"(ta));

        float pr[30] = { q0.x,  q0.y,  q1.x,  q1.y,  q2.x,  q2.y,
                         q3.x,  q3.y,  q4.x,  q4.y,  q5.x,  q5.y,
                         q6.x,  q6.y,  q7.x,  q7.y,  q8.x,  q8.y,
                         q9.x,  q9.y,  q10.x, q10.y, q11.x, q11.y,
                         q12.x, q12.y, q13.x, q13.y, q14.x, q14.y };

        int cell = t * CPW + lane;
        int ij = cell % (S_GRID * S_GRID);
        float gi = (float)(ij / S_GRID);
        float gj = (float)(ij % S_GRID);

        float iou0 = iou_calc(pr[0], pr[1], pr[2], pr[3], tx, ty, tw, th, gi, gj);
        float iou1 = iou_calc(pr[5], pr[6], pr[7], pr[8], tx, ty, tw, th, gi, gj);
        bool choose1 = !(iou0 > iou1);

        float conf_pred = choose1 ? pr[9] : pr[4];
        float conf_true = choose1 ? iou1 : iou0;
        float xp  = choose1 ? pr[5] : pr[0];
        float ypv = choose1 ? pr[6] : pr[1];

        float dcf = conf_pred - conf_true;
        float d0 = xp - tx, d1 = ypv - ty;

        int cls = (int)tc - 1;   // -1 => one-hot all zeros
        float lcls = 0.0f;
#pragma unroll
        for (int k = 0; k < 20; ++k) {
            float oh = (k == cls) ? 1.0f : 0.0f;
            float d = pr[10 + k] - oh;
            lcls += d * d;
        }

        float obj_loss   = dcf * dcf + 5.0f * (d0 * d0 + d1 * d1) + lcls;
        float noobj_loss = 0.5f * (pr[4] * pr[4] + pr[9] * pr[9]);
        acc += (tc != 0.0f) ? obj_loss : noobj_loss;

        buf ^= 1;
    }

    // one wave-local reduction at the end; one partial per wave, NO barrier
#pragma unroll
    for (int off = 32; off > 0; off >>= 1) {
        acc += __shfl_down(acc, off, 64);
    }
    if (lane == 0) partials[gwave] = acc;
}

__global__ __launch_bounds__(256) void reduce_kernel(const float* __restrict__ partials,
                                                     float* __restrict__ out) {
    int tid = threadIdx.x;
    float s = 0.0f;
#pragma unroll
    for (int k = 0; k < 8; ++k) {            // 8 * 256 = 2048 exact
        s += partials[k * 256 + tid];
    }
#pragma unroll
    for (int off = 32; off > 0; off >>= 1) {
        s += __shfl_down(s, off, 64);
    }
    __shared__ float wsum[4];
    int lane = tid & 63;
    int wid  = tid >> 6;
    if (lane == 0) wsum[wid] = s;
    __syncthreads();
    if (tid == 0) {
        out[0] = (wsum[0] + wsum[1] + wsum[2] + wsum[3]) * (1.0f / 1024.0f);
    }
}

extern "C" void kernel_launch(void* const* d_in, const int* in_sizes, int n_in,
                              void* d_out, int out_size, void* d_ws, size_t ws_size,
                              hipStream_t stream) {
    const float* y_pred = (const float*)d_in[0];
    const float* y_true = (const float*)d_in[1];
    float* out = (float*)d_out;
    float* partials = (float*)d_ws;   // 2048 floats, fully overwritten each call

    yolo_loss_kernel<<<NBLOCKS, BLOCK, 0, stream>>>(y_pred, y_true, partials);
    reduce_kernel<<<1, 256, 0, stream>>>(partials, out);
}